// Round 7
// baseline (3667.349 us; speedup 1.0000x reference)
//
#include <hip/hip_runtime.h>
#include <hip/hip_bf16.h>
#include <math.h>

#define D 128
#define EPS 1e-5f

typedef unsigned short u16;
typedef short bf16x8 __attribute__((ext_vector_type(8)));
typedef float f32x4 __attribute__((ext_vector_type(4)));

static __device__ __forceinline__ u16 f2b(float f) {
    union { float f; unsigned u; } x{f};
    unsigned u = x.u;
    return (u16)((u + 0x7FFFu + ((u >> 16) & 1u)) >> 16);   // RNE
}
static __device__ __forceinline__ float bf2f(unsigned ubits) {
    union { unsigned u; float f; } x{ubits << 16};
    return x.f;
}

// async global->LDS, 16B per lane. LDS dest = wave-uniform base + lane*16.
static __device__ __forceinline__ void glds16(const u16* g, u16* l) {
#if __has_builtin(__builtin_amdgcn_global_load_lds)
    __builtin_amdgcn_global_load_lds(
        (const __attribute__((address_space(1))) unsigned int*)g,
        (__attribute__((address_space(3))) unsigned int*)l, 16, 0, 0);
#else
    int lane = threadIdx.x & 63;
    *(uint4*)(l + lane * 8) = *(const uint4*)g;
#endif
}

// ---------------- fused setup: cvt x->bf16 (+zero pad rows), degree, bias concat, stats zero

__global__ __launch_bounds__(256) void setup_kernel(
    const float* __restrict__ x, u16* __restrict__ x16,
    const int* __restrict__ ei, int* __restrict__ cnt,
    const float* __restrict__ bq, const float* __restrict__ bk,
    const float* __restrict__ bv, const float* __restrict__ bs,
    float* __restrict__ bqkvs, float* __restrict__ stats,
    int n4, int n4p, int E)
{
    long total = (long)n4p + E + 512 + 512;
    long stride = (long)gridDim.x * 256;
    for (long i = blockIdx.x * 256L + threadIdx.x; i < total; i += stride) {
        if (i < n4p) {
            uint2 pk = make_uint2(0u, 0u);
            if (i < n4) {
                float4 v = ((const float4*)x)[i];
                pk.x = (unsigned)f2b(v.x) | ((unsigned)f2b(v.y) << 16);
                pk.y = (unsigned)f2b(v.z) | ((unsigned)f2b(v.w) << 16);
            }
            ((uint2*)x16)[i] = pk;
        } else if (i < (long)n4p + E) {
            int e = (int)(i - n4p);
            atomicAdd(&cnt[ei[E + e]], 1);
        } else if (i < (long)n4p + E + 512) {
            int c = (int)(i - n4p - E);
            float b = (c < 128) ? bq[c] : (c < 256) ? bk[c - 128]
                     : (c < 384) ? bv[c - 256] : bs[c - 384];
            bqkvs[c] = b;
        } else {
            stats[i - n4p - E - 512] = 0.f;
        }
    }
}

// ---------------- CSR scan/fill ----------------

__global__ void scan1_kernel(const int* __restrict__ cnt, int* __restrict__ rp1,
                             int* __restrict__ bsum, int Nn) {
    __shared__ int sh[256];
    int i = blockIdx.x * 256 + threadIdx.x;
    int x = (i < Nn) ? cnt[i] : 0;
    sh[threadIdx.x] = x;
    __syncthreads();
    for (int off = 1; off < 256; off <<= 1) {
        int t = (threadIdx.x >= off) ? sh[threadIdx.x - off] : 0;
        __syncthreads();
        sh[threadIdx.x] += t;
        __syncthreads();
    }
    if (i < Nn) rp1[i] = sh[threadIdx.x];
    if (threadIdx.x == 255) bsum[blockIdx.x] = sh[255];
}

__global__ void scan2_kernel(int* __restrict__ bsum, int nb) {
    __shared__ int sh[256];
    int tid = threadIdx.x;
    int x = (tid < nb) ? bsum[tid] : 0;
    sh[tid] = x;
    __syncthreads();
    for (int off = 1; off < 256; off <<= 1) {
        int t = (tid >= off) ? sh[tid - off] : 0;
        __syncthreads();
        sh[tid] += t;
        __syncthreads();
    }
    if (tid < nb) bsum[tid] = sh[tid] - x;   // exclusive
}

__global__ void scan3_kernel(int* __restrict__ row_ptr, const int* __restrict__ bsum, int Nn) {
    int i = blockIdx.x * 256 + threadIdx.x;
    if (i < Nn) row_ptr[i + 1] += bsum[blockIdx.x];
    if (i == 0) row_ptr[0] = 0;
}

__global__ void fill_kernel(const int* __restrict__ ei, const int* __restrict__ row_ptr,
                            int* __restrict__ cur, int* __restrict__ colA, int E) {
    int e = blockIdx.x * 256 + threadIdx.x;
    if (e >= E) return;
    int s = ei[e];
    int d = ei[E + e];
    int pos = row_ptr[d] + atomicAdd(&cur[d], 1);
    colA[pos] = s;
}

// ---------------- weights -> bf16 transposed (Wqkvs, WO, W2), one dispatch ------
// wt layout: Wqkvs[512][128]@0 | WO[128][128]@65536 | W2[128][256]@81920 | W1'[256][128]@114688

__global__ void wprep_kernel(
    const float* __restrict__ Wq, const float* __restrict__ Wk,
    const float* __restrict__ Wv, const float* __restrict__ Ws,
    const float* __restrict__ WO, const float* __restrict__ W2,
    u16* __restrict__ wt)
{
    int b = blockIdx.x;
    const float* src; u16* dst; int K, Nout;
    if (b < 64)      { int w = b >> 4; b &= 15; K = 128; Nout = 128;
                       src = (w == 0) ? Wq : (w == 1) ? Wk : (w == 2) ? Wv : Ws;
                       dst = wt + w * 16384; }
    else if (b < 80) { b -= 64; K = 128; Nout = 128; src = WO; dst = wt + 65536; }
    else             { b -= 80; K = 256; Nout = 128; src = W2; dst = wt + 81920; }
    int nx = Nout >> 5;
    int bx = (b % nx) * 32, by = (b / nx) * 32;

    __shared__ u16 t[32][33];
    int tx = threadIdx.x, ty = threadIdx.y;
    #pragma unroll
    for (int r = 0; r < 32; r += 8)
        t[ty + r][tx] = f2b(src[(size_t)(by + ty + r) * Nout + bx + tx]);
    __syncthreads();
    #pragma unroll
    for (int r = 0; r < 32; r += 8)
        dst[(size_t)(bx + ty + r) * K + by + tx] = t[tx][ty + r];
}

// ---------------- prep1: BN1 coeffs + fold into W1 (bf16 BT) + b1' --------------
// ab1[c]=a, ab1[128+c]=c. W1'[j][k] = bf16(a[k]*W1[k][j]). b1'[j] = b1[j] + sum_k c[k]*W1[k][j].

__global__ void prep1_kernel(const float* __restrict__ stats,
                             const float* __restrict__ g1, const float* __restrict__ be1,
                             const float* __restrict__ W1, const float* __restrict__ b1,
                             float* __restrict__ ab1, u16* __restrict__ w1t,
                             float* __restrict__ b1p, float invN)
{
    __shared__ float a_sh[128], c_sh[128];
    int t = threadIdx.x;   // 256
    if (t < 128) {
        float mean = stats[t] * invN;
        float var = stats[128 + t] * invN - mean * mean;
        float a = g1[t] * rsqrtf(var + EPS);
        float c = be1[t] - a * mean;
        ab1[t] = a; ab1[128 + t] = c;
        a_sh[t] = a; c_sh[t] = c;
    }
    __syncthreads();
    float acc = b1[t];
    for (int k = 0; k < 128; ++k) {
        float w = W1[(size_t)k * 256 + t];
        w1t[(size_t)t * 128 + k] = f2b(w * a_sh[k]);
        acc += c_sh[k] * w;
    }
    b1p[t] = acc;
}

// ---------------- bf16 MFMA GEMM, 64x64 tile (high-TLP) ------------------------
// A [Mpad][K] bf16 tight, BT [Nout][K] bf16 tight. 4 waves; wave w owns output
// cols w*16..w*16+15, all 64 rows (4 frags of 16x16x32). glds16 staging with XOR
// chunk swizzle on the global side -> conflict-free ds_read_b128. Epilogue stages
// fp32 tile in LDS (stride 68 -> 16B-aligned rows), single-pass coalesced writeout:
// thread = (row=tid>>2, 16 cols). RES: 0 none, 1 fp32, 3 bf16-with-bn(a,c in abp).

#define GTM 64
#define GTK 64
#define ELDW 68

template<int RES, bool OUT16, bool STATS, bool RELU>
__global__ __launch_bounds__(256) void gemm_k(
    const u16* __restrict__ A, const u16* __restrict__ BT,
    const float* __restrict__ bias,
    const void* __restrict__ res, int ldres,
    const float* __restrict__ abp,
    void* __restrict__ Cout, int ldc,
    float* __restrict__ stats, int M, int K)
{
    __shared__ float smem[GTM * ELDW];           // 17408 B (unions tiles + epilogue)
    u16* As = (u16*)smem;                        // [64][64] bf16 = 8KB
    u16* Bs = As + GTM * GTK;                    // 8KB

    int tid = threadIdx.x;
    int wave = tid >> 6;
    int lane = tid & 63;
    int lrow = lane & 15;
    int lquad = lane >> 4;
    int lrow8 = lane >> 3;
    int ch = (lane & 7) ^ lrow8;                 // xor-swizzled global chunk
    int bm = blockIdx.x * GTM;
    int bn = blockIdx.y * GTM;

    const u16* Ag = A + (size_t)(bm + wave * 16 + lrow8) * K + ch * 8;
    const u16* Bg = BT + (size_t)(bn + wave * 16 + lrow8) * K + ch * 8;
    u16* Al = As + wave * 16 * GTK;
    u16* Bl = Bs + wave * 16 * GTK;

    f32x4 acc[4];
    #pragma unroll
    for (int i = 0; i < 4; ++i) acc[i] = (f32x4)0.f;

    for (int kc = 0; kc < K; kc += GTK) {
        #pragma unroll
        for (int t = 0; t < 2; ++t) {
            glds16(Ag + (size_t)(t * 8) * K + kc, Al + t * 8 * GTK);
            glds16(Bg + (size_t)(t * 8) * K + kc, Bl + t * 8 * GTK);
        }
        __syncthreads();
        #pragma unroll
        for (int ks = 0; ks < 2; ++ks) {
            int cfr = ((ks * 4 + lquad) ^ (lrow & 7)) * 8;
            bf16x8 bfr = *(const bf16x8*)&Bs[(wave * 16 + lrow) * GTK + cfr];
            #pragma unroll
            for (int i = 0; i < 4; ++i) {
                bf16x8 af = *(const bf16x8*)&As[(i * 16 + lrow) * GTK + cfr];
                acc[i] = __builtin_amdgcn_mfma_f32_16x16x32_bf16(bfr, af, acc[i], 0, 0, 0);
            }
        }
        __syncthreads();
    }

    // stage fp32 tile: lane's acc[i] = C[row=i*16+lrow][cols wave*16+lquad*4 ..+3]
    #pragma unroll
    for (int i = 0; i < 4; ++i)
        *(f32x4*)&smem[(i * 16 + lrow) * ELDW + wave * 16 + lquad * 4] = acc[i];
    __syncthreads();

    // writeout: thread covers row tid>>2, cols (tid&3)*16 .. +15
    int row = tid >> 2, colg = (tid & 3) * 16;
    int grow = bm + row, gcol = bn + colg;
    float o[16];
    #pragma unroll
    for (int q = 0; q < 4; ++q)
        *(f32x4*)&o[q * 4] = *(const f32x4*)&smem[row * ELDW + colg + q * 4];
    #pragma unroll
    for (int q = 0; q < 4; ++q) {
        float4 bv = *(const float4*)&bias[gcol + q * 4];
        o[q * 4] += bv.x; o[q * 4 + 1] += bv.y; o[q * 4 + 2] += bv.z; o[q * 4 + 3] += bv.w;
    }
    bool valid = grow < M;
    if (valid) {
        if constexpr (RES == 1) {
            const float* rp = (const float*)res + (size_t)grow * ldres + gcol;
            #pragma unroll
            for (int q = 0; q < 4; ++q) {
                float4 rv = *(const float4*)(rp + q * 4);
                o[q * 4] += rv.x; o[q * 4 + 1] += rv.y; o[q * 4 + 2] += rv.z; o[q * 4 + 3] += rv.w;
            }
        }
        if constexpr (RES == 3) {
            const u16* rp = (const u16*)res + (size_t)grow * ldres + gcol;
            uint4 h0 = *(const uint4*)rp;
            uint4 h1 = *(const uint4*)(rp + 8);
            float hv[16] = {
                bf2f(h0.x & 0xffffu), bf2f(h0.x >> 16), bf2f(h0.y & 0xffffu), bf2f(h0.y >> 16),
                bf2f(h0.z & 0xffffu), bf2f(h0.z >> 16), bf2f(h0.w & 0xffffu), bf2f(h0.w >> 16),
                bf2f(h1.x & 0xffffu), bf2f(h1.x >> 16), bf2f(h1.y & 0xffffu), bf2f(h1.y >> 16),
                bf2f(h1.z & 0xffffu), bf2f(h1.z >> 16), bf2f(h1.w & 0xffffu), bf2f(h1.w >> 16)};
            #pragma unroll
            for (int q = 0; q < 4; ++q) {
                float4 av = *(const float4*)&abp[gcol + q * 4];
                float4 cv = *(const float4*)&abp[128 + gcol + q * 4];
                o[q * 4]     += av.x * hv[q * 4]     + cv.x;
                o[q * 4 + 1] += av.y * hv[q * 4 + 1] + cv.y;
                o[q * 4 + 2] += av.z * hv[q * 4 + 2] + cv.z;
                o[q * 4 + 3] += av.w * hv[q * 4 + 3] + cv.w;
            }
        }
        if constexpr (RELU) {
            #pragma unroll
            for (int r = 0; r < 16; ++r) o[r] = fmaxf(o[r], 0.f);
        }
        if constexpr (OUT16) {
            u16* cp = (u16*)Cout + (size_t)grow * ldc + gcol;
            uint4 pk0, pk1;
            pk0.x = (unsigned)f2b(o[0]) | ((unsigned)f2b(o[1]) << 16);
            pk0.y = (unsigned)f2b(o[2]) | ((unsigned)f2b(o[3]) << 16);
            pk0.z = (unsigned)f2b(o[4]) | ((unsigned)f2b(o[5]) << 16);
            pk0.w = (unsigned)f2b(o[6]) | ((unsigned)f2b(o[7]) << 16);
            pk1.x = (unsigned)f2b(o[8]) | ((unsigned)f2b(o[9]) << 16);
            pk1.y = (unsigned)f2b(o[10]) | ((unsigned)f2b(o[11]) << 16);
            pk1.z = (unsigned)f2b(o[12]) | ((unsigned)f2b(o[13]) << 16);
            pk1.w = (unsigned)f2b(o[14]) | ((unsigned)f2b(o[15]) << 16);
            *(uint4*)cp = pk0;
            *(uint4*)(cp + 8) = pk1;
        } else {
            float* cp = (float*)Cout + (size_t)grow * ldc + gcol;
            #pragma unroll
            for (int q = 0; q < 4; ++q)
                *(float4*)(cp + q * 4) = make_float4(o[q * 4], o[q * 4 + 1], o[q * 4 + 2], o[q * 4 + 3]);
        }
    }
    if constexpr (STATS) {
        float ss[16], sq[16];
        #pragma unroll
        for (int r = 0; r < 16; ++r) {
            float v = valid ? o[r] : 0.f;
            ss[r] = v; sq[r] = v * v;
        }
        #pragma unroll
        for (int off = 4; off < 64; off <<= 1) {
            #pragma unroll
            for (int r = 0; r < 16; ++r) {
                ss[r] += __shfl_xor(ss[r], off);
                sq[r] += __shfl_xor(sq[r], off);
            }
        }
        if (lane < 4) {
            int c = bn + lane * 16;
            #pragma unroll
            for (int r = 0; r < 16; ++r) {
                atomicAdd(&stats[c + r], ss[r]);
                atomicAdd(&stats[128 + c + r], sq[r]);
            }
        }
    }
}

// ---------------- attention: one wave per dst node, online softmax, unroll 4 ------
// qkvs row layout: [q(128)|k(128)|v(128)|t_init(128)] bf16, stride 512. Output to t16.

__global__ __launch_bounds__(256) void attn_kernel(
    const u16* __restrict__ qkvs, const int* __restrict__ row_ptr,
    const int* __restrict__ colA, u16* __restrict__ t16, int Nn)
{
    int wave = threadIdx.x >> 6;
    int lane = threadIdx.x & 63;
    int n = blockIdx.x * 4 + wave;
    if (n >= Nn) return;

    int beg = row_ptr[n], end = row_ptr[n + 1];
    const u16* qr = qkvs + (size_t)n * 512;
    unsigned qu = *(const unsigned*)&qr[lane * 2];
    float q0 = bf2f(qu & 0xffffu), q1 = bf2f(qu >> 16);

    const float scale = 0.08838834764831845f;   // 1/sqrt(128)
    float m = -INFINITY, l = 0.f, a0 = 0.f, a1 = 0.f;

#define ATTN_UPD(dd, vv)                                              \
    {                                                                 \
        float sc = (dd) * scale;                                      \
        float nm = fmaxf(m, sc);                                      \
        float co = __expf(m - nm), p = __expf(sc - nm);               \
        l = l * co + p;                                               \
        a0 = a0 * co + p * bf2f((vv) & 0xffffu);                      \
        a1 = a1 * co + p * bf2f((vv) >> 16);                          \
        m = nm;                                                       \
    }

    int i = beg;
    for (; i + 4 <= end; i += 4) {
        int s0 = colA[i], s1 = colA[i + 1], s2 = colA[i + 2], s3 = colA[i + 3];
        const u16* b0 = qkvs + (size_t)s0 * 512;
        const u16* b1 = qkvs + (size_t)s1 * 512;
        const u16* b2 = qkvs + (size_t)s2 * 512;
        const u16* b3 = qkvs + (size_t)s3 * 512;
        unsigned k0 = *(const unsigned*)&b0[128 + lane * 2];
        unsigned k1 = *(const unsigned*)&b1[128 + lane * 2];
        unsigned k2 = *(const unsigned*)&b2[128 + lane * 2];
        unsigned k3 = *(const unsigned*)&b3[128 + lane * 2];
        unsigned v0 = *(const unsigned*)&b0[256 + lane * 2];
        unsigned v1 = *(const unsigned*)&b1[256 + lane * 2];
        unsigned v2 = *(const unsigned*)&b2[256 + lane * 2];
        unsigned v3 = *(const unsigned*)&b3[256 + lane * 2];
        float d0 = q0 * bf2f(k0 & 0xffffu) + q1 * bf2f(k0 >> 16);
        float d1 = q0 * bf2f(k1 & 0xffffu) + q1 * bf2f(k1 >> 16);
        float d2 = q0 * bf2f(k2 & 0xffffu) + q1 * bf2f(k2 >> 16);
        float d3 = q0 * bf2f(k3 & 0xffffu) + q1 * bf2f(k3 >> 16);
        #pragma unroll
        for (int off = 32; off; off >>= 1) {
            d0 += __shfl_xor(d0, off);
            d1 += __shfl_xor(d1, off);
            d2 += __shfl_xor(d2, off);
            d3 += __shfl_xor(d3, off);
        }
        ATTN_UPD(d0, v0); ATTN_UPD(d1, v1); ATTN_UPD(d2, v2); ATTN_UPD(d3, v3);
    }
    for (; i < end; ++i) {
        int s = colA[i];
        const u16* bp = qkvs + (size_t)s * 512;
        unsigned ku = *(const unsigned*)&bp[128 + lane * 2];
        unsigned vu = *(const unsigned*)&bp[256 + lane * 2];
        float d = q0 * bf2f(ku & 0xffffu) + q1 * bf2f(ku >> 16);
        #pragma unroll
        for (int off = 32; off; off >>= 1) d += __shfl_xor(d, off);
        ATTN_UPD(d, vu);
    }
#undef ATTN_UPD

    unsigned tu = *(const unsigned*)&qr[384 + lane * 2];
    float t0 = bf2f(tu & 0xffffu), t1 = bf2f(tu >> 16);
    if (l > 0.f) {
        float inv = 1.f / l;
        t0 += a0 * inv;
        t1 += a1 * inv;
    }
    *(unsigned*)&t16[(size_t)n * 128 + lane * 2] =
        (unsigned)f2b(t0) | ((unsigned)f2b(t1) << 16);
}

// ---------------- BN2: prep + apply ----------------

__global__ void bnprep_kernel(const float* __restrict__ stats,
                              const float* __restrict__ g, const float* __restrict__ be,
                              float* __restrict__ ab, float invN) {
    int c = threadIdx.x;   // 128 threads
    float mean = stats[c] * invN;
    float var = stats[128 + c] * invN - mean * mean;
    float a = g[c] * rsqrtf(var + EPS);
    ab[c] = a;
    ab[128 + c] = be[c] - a * mean;
}

__global__ __launch_bounds__(256) void bn_apply_kernel(
    const float* __restrict__ h, const float* __restrict__ ab,
    float* __restrict__ out, int total4)
{
    int stride = gridDim.x * 256;
    for (int i4 = blockIdx.x * 256 + threadIdx.x; i4 < total4; i4 += stride) {
        int cb = (i4 & 31) * 4;
        float4 x = ((const float4*)h)[i4];
        float o0 = ab[cb] * x.x + ab[128 + cb];
        float o1 = ab[cb + 1] * x.y + ab[128 + cb + 1];
        float o2 = ab[cb + 2] * x.z + ab[128 + cb + 2];
        float o3 = ab[cb + 3] * x.w + ab[128 + cb + 3];
        ((float4*)out)[i4] = make_float4(o0, o1, o2, o3);
    }
}

// ---------------- launch ----------------

extern "C" void kernel_launch(void* const* d_in, const int* in_sizes, int n_in,
                              void* d_out, int out_size, void* d_ws, size_t ws_size,
                              hipStream_t stream) {
    const float* x  = (const float*)d_in[0];
    const int*   ei = (const int*)d_in[1];
    const float* Wq = (const float*)d_in[2];  const float* bq = (const float*)d_in[3];
    const float* Wk = (const float*)d_in[4];  const float* bk = (const float*)d_in[5];
    const float* Wv = (const float*)d_in[6];  const float* bv = (const float*)d_in[7];
    const float* Ws = (const float*)d_in[8];  const float* bs = (const float*)d_in[9];
    const float* WO = (const float*)d_in[10]; const float* bO = (const float*)d_in[11];
    const float* W1 = (const float*)d_in[12]; const float* b1 = (const float*)d_in[13];
    const float* W2 = (const float*)d_in[14]; const float* b2 = (const float*)d_in[15];
    const float* g1 = (const float*)d_in[16]; const float* be1 = (const float*)d_in[17];
    const float* g2 = (const float*)d_in[18]; const float* be2 = (const float*)d_in[19];

    const int N = in_sizes[0] / D;            // 50000
    const int E = in_sizes[1] / 2;            // 800000
    float* out = (float*)d_out;

    int gm = (N + GTM - 1) / GTM;             // 782
    int Npad = gm * GTM;                      // 50048
    size_t NDp = (size_t)Npad * D;

    // ---- workspace (~85 MB) ----
    u16* x16 = (u16*)d_ws;                    // [Npad][128]; pad rows zeroed
    u16* qkvs = x16 + NDp;                    // [Npad][512]
    u16* h16 = qkvs + (size_t)Npad * 512;     // [Npad][128] (rows >= N stay poison: benign, deterministic)
    float* stats = (float*)(h16 + NDp);       // 512 (BN1 | BN2)
    float* ab1 = stats + 512;                 // 256
    float* ab2 = ab1 + 256;                   // 256
    float* bqkvs = ab2 + 256;                 // 512
    float* b1p = bqkvs + 512;                 // 256
    u16* wt = (u16*)(b1p + 256);              // 147456: qkvs|WO|W2|W1'
    int* row_ptr = (int*)(wt + 147456);       // N+1
    int* cnt = row_ptr + (N + 1);             // N
    int* cur = cnt + N;                       // N
    int* colA = cur + N;                      // E
    int* bsum = colA + E;                     // <=256
    // aliases:
    u16* t16 = x16;                           // x16 dead after QKVS; pad rows stay 0
    u16* zb16 = qkvs;                         // [Npad][256], qkvs dead after attn
    float* h2 = (float*)(qkvs + (size_t)Npad * 256);   // [N][128] fp32, disjoint from zb16

    int nb = (N + 255) / 256;
    int eb = (E + 255) / 256;

    // --- setup + CSR ---
    hipMemsetAsync(cnt, 0, (size_t)2 * N * sizeof(int), stream);
    setup_kernel<<<1024, 256, 0, stream>>>(x, x16, ei, cnt, bq, bk, bv, bs,
                                           bqkvs, stats, N * 32, Npad * 32, E);
    wprep_kernel<<<112, dim3(32, 8), 0, stream>>>(Wq, Wk, Wv, Ws, WO, W2, wt);
    scan1_kernel<<<nb, 256, 0, stream>>>(cnt, row_ptr + 1, bsum, N);
    scan2_kernel<<<1, 256, 0, stream>>>(bsum, nb);
    scan3_kernel<<<nb, 256, 0, stream>>>(row_ptr, bsum, N);
    fill_kernel<<<eb, 256, 0, stream>>>(ei, row_ptr, cur, colA, E);

    // --- QKVS: qkvs[Npad][512] bf16 ---
    gemm_k<0, true, false, false><<<dim3(gm, 8), 256, 0, stream>>>(
        x16, wt, bqkvs, nullptr, 0, nullptr, qkvs, 512, nullptr, Npad, 128);

    // --- attention: t16 = t_init + softmax-agg(v) ---
    attn_kernel<<<(N + 3) / 4, 256, 0, stream>>>(qkvs, row_ptr, colA, t16, N);

    // --- O-proj + residual1 + BN1 stats: h16 = bf16(x + t16@WO + bO) ---
    gemm_k<1, true, true, false><<<dim3(gm, 2), 256, 0, stream>>>(
        t16, wt + 65536, bO, x, 128, nullptr, h16, 128, stats, N, 128);

    // --- prep1: ab1, W1' (bf16, folded BN1), b1' ---
    prep1_kernel<<<1, 256, 0, stream>>>(stats, g1, be1, W1, b1, ab1, wt + 114688, b1p,
                                        1.f / (float)N);

    // --- FFN1: zb16 = relu(h16@W1' + b1') ---
    gemm_k<0, true, false, true><<<dim3(gm, 4), 256, 0, stream>>>(
        h16, wt + 114688, b1p, nullptr, 0, nullptr, zb16, 256, nullptr, Npad, 128);

    // --- FFN2 + residual2(bn1 inline) + BN2 stats: h2 = (a1*h16+c1) + zb16@W2 + b2 ---
    gemm_k<3, false, true, false><<<dim3(gm, 2), 256, 0, stream>>>(
        zb16, wt + 81920, b2, h16, 128, ab1, h2, 128, stats + 256, N, 256);

    // --- BN2 apply -> out ---
    bnprep_kernel<<<1, 128, 0, stream>>>(stats + 256, g2, be2, ab2, 1.f / (float)N);
    bn_apply_kernel<<<1024, 256, 0, stream>>>(h2, ab2, out, N * 32);
}

// Round 8
// 373.666 us; speedup vs baseline: 9.8145x; 9.8145x over previous
//
#include <hip/hip_runtime.h>
#include <hip/hip_bf16.h>
#include <math.h>

#define D 128
#define EPS 1e-5f

typedef unsigned short u16;
typedef short bf16x8 __attribute__((ext_vector_type(8)));
typedef float f32x4 __attribute__((ext_vector_type(4)));

static __device__ __forceinline__ u16 f2b(float f) {
    union { float f; unsigned u; } x{f};
    unsigned u = x.u;
    return (u16)((u + 0x7FFFu + ((u >> 16) & 1u)) >> 16);   // RNE
}
static __device__ __forceinline__ float bf2f(unsigned ubits) {
    union { unsigned u; float f; } x{ubits << 16};
    return x.f;
}

// async global->LDS, 16B per lane. LDS dest = wave-uniform base + lane*16.
static __device__ __forceinline__ void glds16(const u16* g, u16* l) {
#if __has_builtin(__builtin_amdgcn_global_load_lds)
    __builtin_amdgcn_global_load_lds(
        (const __attribute__((address_space(1))) unsigned int*)g,
        (__attribute__((address_space(3))) unsigned int*)l, 16, 0, 0);
#else
    int lane = threadIdx.x & 63;
    *(uint4*)(l + lane * 8) = *(const uint4*)g;
#endif
}

// ---------------- fused setup: cvt x->bf16 (+zero pad rows), degree, bias concat, stats zero

__global__ __launch_bounds__(256) void setup_kernel(
    const float* __restrict__ x, u16* __restrict__ x16,
    const int* __restrict__ ei, int* __restrict__ cnt,
    const float* __restrict__ bq, const float* __restrict__ bk,
    const float* __restrict__ bv, const float* __restrict__ bs,
    float* __restrict__ bqkvs, float* __restrict__ stats,
    int n4, int n4p, int E)
{
    long total = (long)n4p + E + 512 + 512;
    long stride = (long)gridDim.x * 256;
    for (long i = blockIdx.x * 256L + threadIdx.x; i < total; i += stride) {
        if (i < n4p) {
            uint2 pk = make_uint2(0u, 0u);
            if (i < n4) {
                float4 v = ((const float4*)x)[i];
                pk.x = (unsigned)f2b(v.x) | ((unsigned)f2b(v.y) << 16);
                pk.y = (unsigned)f2b(v.z) | ((unsigned)f2b(v.w) << 16);
            }
            ((uint2*)x16)[i] = pk;
        } else if (i < (long)n4p + E) {
            int e = (int)(i - n4p);
            atomicAdd(&cnt[ei[E + e]], 1);
        } else if (i < (long)n4p + E + 512) {
            int c = (int)(i - n4p - E);
            float b = (c < 128) ? bq[c] : (c < 256) ? bk[c - 128]
                     : (c < 384) ? bv[c - 256] : bs[c - 384];
            bqkvs[c] = b;
        } else {
            stats[i - n4p - E - 512] = 0.f;
        }
    }
}

// ---------------- CSR scan/fill ----------------

__global__ void scan1_kernel(const int* __restrict__ cnt, int* __restrict__ rp1,
                             int* __restrict__ bsum, int Nn) {
    __shared__ int sh[256];
    int i = blockIdx.x * 256 + threadIdx.x;
    int x = (i < Nn) ? cnt[i] : 0;
    sh[threadIdx.x] = x;
    __syncthreads();
    for (int off = 1; off < 256; off <<= 1) {
        int t = (threadIdx.x >= off) ? sh[threadIdx.x - off] : 0;
        __syncthreads();
        sh[threadIdx.x] += t;
        __syncthreads();
    }
    if (i < Nn) rp1[i] = sh[threadIdx.x];
    if (threadIdx.x == 255) bsum[blockIdx.x] = sh[255];
}

__global__ void scan2_kernel(int* __restrict__ bsum, int nb) {
    __shared__ int sh[256];
    int tid = threadIdx.x;
    int x = (tid < nb) ? bsum[tid] : 0;
    sh[tid] = x;
    __syncthreads();
    for (int off = 1; off < 256; off <<= 1) {
        int t = (tid >= off) ? sh[tid - off] : 0;
        __syncthreads();
        sh[tid] += t;
        __syncthreads();
    }
    if (tid < nb) bsum[tid] = sh[tid] - x;   // exclusive
}

__global__ void scan3_kernel(int* __restrict__ row_ptr, const int* __restrict__ bsum, int Nn) {
    int i = blockIdx.x * 256 + threadIdx.x;
    if (i < Nn) row_ptr[i + 1] += bsum[blockIdx.x];
    if (i == 0) row_ptr[0] = 0;
}

__global__ void fill_kernel(const int* __restrict__ ei, const int* __restrict__ row_ptr,
                            int* __restrict__ cur, int* __restrict__ colA, int E) {
    int e = blockIdx.x * 256 + threadIdx.x;
    if (e >= E) return;
    int s = ei[e];
    int d = ei[E + e];
    int pos = row_ptr[d] + atomicAdd(&cur[d], 1);
    colA[pos] = s;
}

// ---------------- weights -> bf16 transposed (Wqkvs, WO, W2), one dispatch ------
// wt layout: Wqkvs[512][128]@0 | WO[128][128]@65536 | W2[128][256]@81920 | W1'[256][128]@114688

__global__ void wprep_kernel(
    const float* __restrict__ Wq, const float* __restrict__ Wk,
    const float* __restrict__ Wv, const float* __restrict__ Ws,
    const float* __restrict__ WO, const float* __restrict__ W2,
    u16* __restrict__ wt)
{
    int b = blockIdx.x;
    const float* src; u16* dst; int K, Nout;
    if (b < 64)      { int w = b >> 4; b &= 15; K = 128; Nout = 128;
                       src = (w == 0) ? Wq : (w == 1) ? Wk : (w == 2) ? Wv : Ws;
                       dst = wt + w * 16384; }
    else if (b < 80) { b -= 64; K = 128; Nout = 128; src = WO; dst = wt + 65536; }
    else             { b -= 80; K = 256; Nout = 128; src = W2; dst = wt + 81920; }
    int nx = Nout >> 5;
    int bx = (b % nx) * 32, by = (b / nx) * 32;

    __shared__ u16 t[32][33];
    int tx = threadIdx.x, ty = threadIdx.y;
    #pragma unroll
    for (int r = 0; r < 32; r += 8)
        t[ty + r][tx] = f2b(src[(size_t)(by + ty + r) * Nout + bx + tx]);
    __syncthreads();
    #pragma unroll
    for (int r = 0; r < 32; r += 8)
        dst[(size_t)(bx + ty + r) * K + by + tx] = t[tx][ty + r];
}

// ---------------- prep1: BN1 coeffs + fold into W1' (bf16 BT) + b1' -------------
// ab1[c]=a, ab1[128+c]=c. W1'[j][k] = bf16(a[k]*W1[k][j]). b1'[j] = b1[j] + sum_k c[k]*W1[k][j].

__global__ void prep1_kernel(const float* __restrict__ stats,
                             const float* __restrict__ g1, const float* __restrict__ be1,
                             const float* __restrict__ W1, const float* __restrict__ b1,
                             float* __restrict__ ab1, u16* __restrict__ w1t,
                             float* __restrict__ b1p, float invN)
{
    __shared__ float a_sh[128], c_sh[128];
    int t = threadIdx.x;   // 256
    if (t < 128) {
        float mean = stats[t] * invN;
        float var = stats[128 + t] * invN - mean * mean;
        float a = g1[t] * rsqrtf(var + EPS);
        float c = be1[t] - a * mean;
        ab1[t] = a; ab1[128 + t] = c;
        a_sh[t] = a; c_sh[t] = c;
    }
    __syncthreads();
    float acc = b1[t];
    for (int k = 0; k < 128; ++k) {
        float w = W1[(size_t)k * 256 + t];
        w1t[(size_t)t * 128 + k] = f2b(w * a_sh[k]);
        acc += c_sh[k] * w;
    }
    b1p[t] = acc;
}

// ---------------- bf16 MFMA GEMM (r6-proven 128x128 structure) ------------------
// A [Mpad][K] bf16 tight, BT [Nout][K] bf16 tight. Tile 128x128, BK=64.
// K-loop: glds16 staging (XOR chunk swizzle on global side), conflict-free
// ds_read_b128 fragments. Epilogue: 2 passes of 64 rows staged to LDS (float2,
// stride 132), row-contiguous coalesced writes. Optional in-epilogue BN stats
// (per-thread partials -> shfl 16/32 -> LDS cross-wave reduce -> 256 atomics).
// RES: 0 none, 1 fp32, 2 bf16, 3 bf16-with-bn(a,c in abp).

#define GBM 128
#define GBK 64
#define LDW 132

template<int RES, bool OUT16, bool STATS, bool RELU>
__global__ __launch_bounds__(256) void gemm_k(
    const u16* __restrict__ A, const u16* __restrict__ BT,
    const float* __restrict__ bias,
    const void* __restrict__ res, int ldres,
    const float* __restrict__ abp,
    void* __restrict__ Cout, int ldc,
    float* __restrict__ stats, int M, int K)
{
    __shared__ float smem[64 * LDW];             // 33792 B, unioned: K-loop tiles + epilogue
    __shared__ float stbuf[4][16][16];           // 4096 B, cross-wave stats staging
    u16* As = (u16*)smem;                        // [128][64] bf16 = 16 KB
    u16* Bs = As + GBM * GBK;                    // 16 KB

    int tid = threadIdx.x;
    int wave = tid >> 6;
    int lane = tid & 63;
    int wm = (wave >> 1) * 64;
    int wn = (wave & 1) * 64;
    int bm = blockIdx.x * GBM;
    int bn = blockIdx.y * GBM;
    int lrow = lane & 15;
    int lquad = lane >> 4;

    int lrow8 = lane >> 3;                 // 0..7
    int ch = (lane & 7) ^ lrow8;           // xor-swizzled global chunk
    const u16* Ag = A + (size_t)(bm + wave * 32 + lrow8) * K + ch * 8;
    const u16* Bg = BT + (size_t)(bn + wave * 32 + lrow8) * K + ch * 8;
    u16* Al = As + wave * 32 * GBK;        // wave-uniform LDS bases
    u16* Bl = Bs + wave * 32 * GBK;

    f32x4 acc[4][4];
    #pragma unroll
    for (int i = 0; i < 4; ++i)
        #pragma unroll
        for (int j = 0; j < 4; ++j)
            acc[i][j] = (f32x4)0.f;

    for (int kc = 0; kc < K; kc += GBK) {
        #pragma unroll
        for (int t = 0; t < 4; ++t) {
            glds16(Ag + (size_t)(t * 8) * K + kc, Al + t * 8 * GBK);
            glds16(Bg + (size_t)(t * 8) * K + kc, Bl + t * 8 * GBK);
        }
        __syncthreads();
        #pragma unroll
        for (int ks = 0; ks < 2; ++ks) {
            int cfr = ((ks * 4 + lquad) ^ (lrow & 7)) * 8;
            bf16x8 af[4], bfr[4];
            #pragma unroll
            for (int i = 0; i < 4; ++i)
                af[i] = *(const bf16x8*)&As[(wm + i * 16 + lrow) * GBK + cfr];
            #pragma unroll
            for (int j = 0; j < 4; ++j)
                bfr[j] = *(const bf16x8*)&Bs[(wn + j * 16 + lrow) * GBK + cfr];
            // swapped operands: lane holds row = ...+lrow, cols = ...+lquad*4+r
            #pragma unroll
            for (int i = 0; i < 4; ++i)
                #pragma unroll
                for (int j = 0; j < 4; ++j)
                    acc[i][j] = __builtin_amdgcn_mfma_f32_16x16x32_bf16(bfr[j], af[i], acc[i][j], 0, 0, 0);
        }
        __syncthreads();
    }

    // ---- 2-pass epilogue: stage 64 rows, coalesced writeout ----
    int colg = (tid & 15) * 8;
    int gcol = bn + colg;
    float4 bs0 = *(const float4*)&bias[gcol];
    float4 bs1 = *(const float4*)&bias[gcol + 4];
    float bs8[8] = {bs0.x, bs0.y, bs0.z, bs0.w, bs1.x, bs1.y, bs1.z, bs1.w};

    float ss[8], sq[8];
    if constexpr (STATS) {
        #pragma unroll
        for (int r = 0; r < 8; ++r) { ss[r] = 0.f; sq[r] = 0.f; }
    }

    #pragma unroll
    for (int p = 0; p < 2; ++p) {
        if ((wave >> 1) == p) {
            #pragma unroll
            for (int i = 0; i < 4; ++i)
                #pragma unroll
                for (int j = 0; j < 4; ++j) {
                    int off = (i * 16 + lrow) * LDW + wn + j * 16 + lquad * 4;
                    *(float2*)&smem[off]     = make_float2(acc[i][j][0], acc[i][j][1]);
                    *(float2*)&smem[off + 2] = make_float2(acc[i][j][2], acc[i][j][3]);
                }
        }
        __syncthreads();
        #pragma unroll
        for (int it = 0; it < 4; ++it) {
            int rl = it * 16 + (tid >> 4);
            int grow = bm + p * 64 + rl;
            if (grow < M) {
                float o[8];
                float2 a0 = *(const float2*)&smem[rl * LDW + colg];
                float2 a1 = *(const float2*)&smem[rl * LDW + colg + 2];
                float2 a2 = *(const float2*)&smem[rl * LDW + colg + 4];
                float2 a3 = *(const float2*)&smem[rl * LDW + colg + 6];
                o[0] = a0.x + bs8[0]; o[1] = a0.y + bs8[1];
                o[2] = a1.x + bs8[2]; o[3] = a1.y + bs8[3];
                o[4] = a2.x + bs8[4]; o[5] = a2.y + bs8[5];
                o[6] = a3.x + bs8[6]; o[7] = a3.y + bs8[7];
                if constexpr (RES == 1) {
                    const float* rp = (const float*)res + (size_t)grow * ldres + gcol;
                    float4 r0 = *(const float4*)rp;
                    float4 r1 = *(const float4*)(rp + 4);
                    o[0] += r0.x; o[1] += r0.y; o[2] += r0.z; o[3] += r0.w;
                    o[4] += r1.x; o[5] += r1.y; o[6] += r1.z; o[7] += r1.w;
                }
                if constexpr (RES == 2) {
                    const u16* rp = (const u16*)res + (size_t)grow * ldres + gcol;
                    uint4 rv = *(const uint4*)rp;
                    o[0] += bf2f(rv.x & 0xffffu); o[1] += bf2f(rv.x >> 16);
                    o[2] += bf2f(rv.y & 0xffffu); o[3] += bf2f(rv.y >> 16);
                    o[4] += bf2f(rv.z & 0xffffu); o[5] += bf2f(rv.z >> 16);
                    o[6] += bf2f(rv.w & 0xffffu); o[7] += bf2f(rv.w >> 16);
                }
                if constexpr (RES == 3) {
                    const u16* rp = (const u16*)res + (size_t)grow * ldres + gcol;
                    uint4 rv = *(const uint4*)rp;
                    float hv[8] = {
                        bf2f(rv.x & 0xffffu), bf2f(rv.x >> 16),
                        bf2f(rv.y & 0xffffu), bf2f(rv.y >> 16),
                        bf2f(rv.z & 0xffffu), bf2f(rv.z >> 16),
                        bf2f(rv.w & 0xffffu), bf2f(rv.w >> 16)};
                    #pragma unroll
                    for (int q = 0; q < 2; ++q) {
                        float4 av = *(const float4*)&abp[gcol + q * 4];
                        float4 cv = *(const float4*)&abp[128 + gcol + q * 4];
                        o[q * 4]     += av.x * hv[q * 4]     + cv.x;
                        o[q * 4 + 1] += av.y * hv[q * 4 + 1] + cv.y;
                        o[q * 4 + 2] += av.z * hv[q * 4 + 2] + cv.z;
                        o[q * 4 + 3] += av.w * hv[q * 4 + 3] + cv.w;
                    }
                }
                if constexpr (RELU) {
                    #pragma unroll
                    for (int r = 0; r < 8; ++r) o[r] = fmaxf(o[r], 0.f);
                }
                if constexpr (STATS) {
                    #pragma unroll
                    for (int r = 0; r < 8; ++r) { ss[r] += o[r]; sq[r] += o[r] * o[r]; }
                }
                if constexpr (OUT16) {
                    uint4 pk;
                    pk.x = (unsigned)f2b(o[0]) | ((unsigned)f2b(o[1]) << 16);
                    pk.y = (unsigned)f2b(o[2]) | ((unsigned)f2b(o[3]) << 16);
                    pk.z = (unsigned)f2b(o[4]) | ((unsigned)f2b(o[5]) << 16);
                    pk.w = (unsigned)f2b(o[6]) | ((unsigned)f2b(o[7]) << 16);
                    *(uint4*)&((u16*)Cout)[(size_t)grow * ldc + gcol] = pk;
                } else {
                    float* cp = (float*)Cout + (size_t)grow * ldc + gcol;
                    *(float4*)cp = make_float4(o[0], o[1], o[2], o[3]);
                    *(float4*)(cp + 4) = make_float4(o[4], o[5], o[6], o[7]);
                }
            }
        }
        __syncthreads();
    }

    if constexpr (STATS) {
        #pragma unroll
        for (int r = 0; r < 8; ++r) {
            ss[r] += __shfl_xor(ss[r], 16); ss[r] += __shfl_xor(ss[r], 32);
            sq[r] += __shfl_xor(sq[r], 16); sq[r] += __shfl_xor(sq[r], 32);
        }
        if (lane < 16) {
            #pragma unroll
            for (int r = 0; r < 8; ++r) {
                stbuf[wave][lane][r] = ss[r];
                stbuf[wave][lane][8 + r] = sq[r];
            }
        }
        __syncthreads();
        int c16 = tid >> 4, r = tid & 15;
        float v = stbuf[0][c16][r] + stbuf[1][c16][r] + stbuf[2][c16][r] + stbuf[3][c16][r];
        int col = bn + c16 * 8 + (r & 7);
        atomicAdd(&stats[(r < 8 ? 0 : 128) + col], v);
    }
}

// ---------------- attention: one wave per dst node, online softmax, unroll 8 ------
// qkvs row layout: [q(128)|k(128)|v(128)|t_init(128)] bf16, stride 512. Output to t16.

__global__ __launch_bounds__(256) void attn_kernel(
    const u16* __restrict__ qkvs, const int* __restrict__ row_ptr,
    const int* __restrict__ colA, u16* __restrict__ t16, int Nn)
{
    int wave = threadIdx.x >> 6;
    int lane = threadIdx.x & 63;
    int n = blockIdx.x * 4 + wave;
    if (n >= Nn) return;

    int beg = row_ptr[n], end = row_ptr[n + 1];
    const u16* qr = qkvs + (size_t)n * 512;
    unsigned qu = *(const unsigned*)&qr[lane * 2];
    float q0 = bf2f(qu & 0xffffu), q1 = bf2f(qu >> 16);

    const float scale = 0.08838834764831845f;   // 1/sqrt(128)
    float m = -INFINITY, l = 0.f, a0 = 0.f, a1 = 0.f;

#define ATTN_UPD(dd, vv)                                              \
    {                                                                 \
        float sc = (dd) * scale;                                      \
        float nm = fmaxf(m, sc);                                      \
        float co = __expf(m - nm), p = __expf(sc - nm);               \
        l = l * co + p;                                               \
        a0 = a0 * co + p * bf2f((vv) & 0xffffu);                      \
        a1 = a1 * co + p * bf2f((vv) >> 16);                          \
        m = nm;                                                       \
    }

    int i = beg;
    for (; i + 8 <= end; i += 8) {
        unsigned kk[8], vv[8];
        float dd[8];
        #pragma unroll
        for (int u = 0; u < 8; ++u) {
            const u16* bp = qkvs + (size_t)colA[i + u] * 512;
            kk[u] = *(const unsigned*)&bp[128 + lane * 2];
            vv[u] = *(const unsigned*)&bp[256 + lane * 2];
        }
        #pragma unroll
        for (int u = 0; u < 8; ++u)
            dd[u] = q0 * bf2f(kk[u] & 0xffffu) + q1 * bf2f(kk[u] >> 16);
        #pragma unroll
        for (int off = 32; off; off >>= 1)
            #pragma unroll
            for (int u = 0; u < 8; ++u) dd[u] += __shfl_xor(dd[u], off);
        #pragma unroll
        for (int u = 0; u < 8; ++u) ATTN_UPD(dd[u], vv[u]);
    }
    for (; i + 4 <= end; i += 4) {
        unsigned kk[4], vv[4];
        float dd[4];
        #pragma unroll
        for (int u = 0; u < 4; ++u) {
            const u16* bp = qkvs + (size_t)colA[i + u] * 512;
            kk[u] = *(const unsigned*)&bp[128 + lane * 2];
            vv[u] = *(const unsigned*)&bp[256 + lane * 2];
        }
        #pragma unroll
        for (int u = 0; u < 4; ++u)
            dd[u] = q0 * bf2f(kk[u] & 0xffffu) + q1 * bf2f(kk[u] >> 16);
        #pragma unroll
        for (int off = 32; off; off >>= 1)
            #pragma unroll
            for (int u = 0; u < 4; ++u) dd[u] += __shfl_xor(dd[u], off);
        #pragma unroll
        for (int u = 0; u < 4; ++u) ATTN_UPD(dd[u], vv[u]);
    }
    for (; i < end; ++i) {
        const u16* bp = qkvs + (size_t)colA[i] * 512;
        unsigned ku = *(const unsigned*)&bp[128 + lane * 2];
        unsigned vu = *(const unsigned*)&bp[256 + lane * 2];
        float d = q0 * bf2f(ku & 0xffffu) + q1 * bf2f(ku >> 16);
        #pragma unroll
        for (int off = 32; off; off >>= 1) d += __shfl_xor(d, off);
        ATTN_UPD(d, vu);
    }
#undef ATTN_UPD

    unsigned tu = *(const unsigned*)&qr[384 + lane * 2];
    float t0 = bf2f(tu & 0xffffu), t1 = bf2f(tu >> 16);
    if (l > 0.f) {
        float inv = 1.f / l;
        t0 += a0 * inv;
        t1 += a1 * inv;
    }
    *(unsigned*)&t16[(size_t)n * 128 + lane * 2] =
        (unsigned)f2b(t0) | ((unsigned)f2b(t1) << 16);
}

// ---------------- BN2: prep + apply ----------------

__global__ void bnprep_kernel(const float* __restrict__ stats,
                              const float* __restrict__ g, const float* __restrict__ be,
                              float* __restrict__ ab, float invN) {
    int c = threadIdx.x;   // 128 threads
    float mean = stats[c] * invN;
    float var = stats[128 + c] * invN - mean * mean;
    float a = g[c] * rsqrtf(var + EPS);
    ab[c] = a;
    ab[128 + c] = be[c] - a * mean;
}

__global__ __launch_bounds__(256) void bn_apply_kernel(
    const float* __restrict__ h, const float* __restrict__ ab,
    float* __restrict__ out, int total4)
{
    int stride = gridDim.x * 256;
    for (int i4 = blockIdx.x * 256 + threadIdx.x; i4 < total4; i4 += stride) {
        int cb = (i4 & 31) * 4;
        float4 x = ((const float4*)h)[i4];
        float o0 = ab[cb] * x.x + ab[128 + cb];
        float o1 = ab[cb + 1] * x.y + ab[128 + cb + 1];
        float o2 = ab[cb + 2] * x.z + ab[128 + cb + 2];
        float o3 = ab[cb + 3] * x.w + ab[128 + cb + 3];
        ((float4*)out)[i4] = make_float4(o0, o1, o2, o3);
    }
}

// ---------------- launch ----------------

extern "C" void kernel_launch(void* const* d_in, const int* in_sizes, int n_in,
                              void* d_out, int out_size, void* d_ws, size_t ws_size,
                              hipStream_t stream) {
    const float* x  = (const float*)d_in[0];
    const int*   ei = (const int*)d_in[1];
    const float* Wq = (const float*)d_in[2];  const float* bq = (const float*)d_in[3];
    const float* Wk = (const float*)d_in[4];  const float* bk = (const float*)d_in[5];
    const float* Wv = (const float*)d_in[6];  const float* bv = (const float*)d_in[7];
    const float* Ws = (const float*)d_in[8];  const float* bs = (const float*)d_in[9];
    const float* WO = (const float*)d_in[10]; const float* bO = (const float*)d_in[11];
    const float* W1 = (const float*)d_in[12]; const float* b1 = (const float*)d_in[13];
    const float* W2 = (const float*)d_in[14]; const float* b2 = (const float*)d_in[15];
    const float* g1 = (const float*)d_in[16]; const float* be1 = (const float*)d_in[17];
    const float* g2 = (const float*)d_in[18]; const float* be2 = (const float*)d_in[19];

    const int N = in_sizes[0] / D;            // 50000
    const int E = in_sizes[1] / 2;            // 800000
    float* out = (float*)d_out;

    int gm = (N + GBM - 1) / GBM;             // 391
    int Npad = gm * GBM;                      // 50048
    size_t NDp = (size_t)Npad * D;

    // ---- workspace (~68 MB) ----
    u16* buf0 = (u16*)d_ws;                   // [Npad][128]: x16 -> t16 -> h16 (in-place chain)
    u16* qkvs = buf0 + NDp;                   // [Npad][512]
    float* stats = (float*)(qkvs + (size_t)Npad * 512);  // 512 (BN1 | BN2)
    float* ab1 = stats + 512;                 // 256
    float* ab2 = ab1 + 256;                   // 256
    float* bqkvs = ab2 + 256;                 // 512
    float* b1p = bqkvs + 512;                 // 256
    u16* wt = (u16*)(b1p + 256);              // 147456: Wqkvs|WO|W2|W1'
    int* row_ptr = (int*)(wt + 147456);       // N+1
    int* cnt = row_ptr + (N + 1);             // N
    int* cur = cnt + N;                       // N
    int* colA = cur + N;                      // E
    int* bsum = colA + E;                     // <=256
    // aliases:
    u16* x16 = buf0;                          // pad rows zeroed by setup
    u16* t16 = buf0;                          // x16 dead after QKVS; pads stay 0
    u16* h16 = buf0;                          // Oproj writes in-place (grid y=1, row-owned)
    u16* zb16 = qkvs;                         // [Npad][256]; qkvs dead after attn
    float* h2 = (float*)(qkvs + (size_t)Npad * 256);   // [N][128] fp32, disjoint from zb16

    int nb = (N + 255) / 256;
    int eb = (E + 255) / 256;

    // --- setup + CSR ---
    hipMemsetAsync(cnt, 0, (size_t)2 * N * sizeof(int), stream);
    setup_kernel<<<1024, 256, 0, stream>>>(x, x16, ei, cnt, bq, bk, bv, bs,
                                           bqkvs, stats, N * 32, Npad * 32, E);
    wprep_kernel<<<112, dim3(32, 8), 0, stream>>>(Wq, Wk, Wv, Ws, WO, W2, wt);
    scan1_kernel<<<nb, 256, 0, stream>>>(cnt, row_ptr + 1, bsum, N);
    scan2_kernel<<<1, 256, 0, stream>>>(bsum, nb);
    scan3_kernel<<<nb, 256, 0, stream>>>(row_ptr, bsum, N);
    fill_kernel<<<eb, 256, 0, stream>>>(ei, row_ptr, cur, colA, E);

    // --- QKVS: qkvs[Npad][512] bf16 ---
    gemm_k<0, true, false, false><<<dim3(gm, 4), 256, 0, stream>>>(
        x16, wt, bqkvs, nullptr, 0, nullptr, qkvs, 512, nullptr, Npad, 128);

    // --- attention: t16 = t_init + softmax-agg(v), rows < N ---
    attn_kernel<<<(N + 3) / 4, 256, 0, stream>>>(qkvs, row_ptr, colA, t16, N);

    // --- O-proj + residual1 + BN1 stats: h16 = bf16(x + t16@WO + bO), in-place ---
    gemm_k<1, true, true, false><<<dim3(gm, 1), 256, 0, stream>>>(
        t16, wt + 65536, bO, x, 128, nullptr, h16, 128, stats, N, 128);

    // --- prep1: ab1, W1' (bf16, BN1 folded), b1' ---
    prep1_kernel<<<1, 256, 0, stream>>>(stats, g1, be1, W1, b1, ab1, wt + 114688, b1p,
                                        1.f / (float)N);

    // --- FFN1: zb16 = relu(h16@W1' + b1'), all Npad rows (pads -> relu(b1'), defined) ---
    gemm_k<0, true, false, true><<<dim3(gm, 2), 256, 0, stream>>>(
        h16, wt + 114688, b1p, nullptr, 0, nullptr, zb16, 256, nullptr, Npad, 128);

    // --- FFN2 + residual2(bn1 inline) + BN2 stats: h2 = (a1*h16+c1) + zb16@W2 + b2 ---
    gemm_k<3, false, true, false><<<dim3(gm, 1), 256, 0, stream>>>(
        zb16, wt + 81920, b2, h16, 128, ab1, h2, 128, stats + 256, N, 256);

    // --- BN2 apply -> out ---
    bnprep_kernel<<<1, 128, 0, stream>>>(stats + 256, g2, be2, ab2, 1.f / (float)N);
    bn_apply_kernel<<<1024, 256, 0, stream>>>(h2, ab2, out, N * 32);
}